// Round 5
// baseline (499.350 us; speedup 1.0000x reference)
//
#include <hip/hip_runtime.h>
#include <hip/hip_cooperative_groups.h>
#include <cstdint>

namespace cg = cooperative_groups;

#define DI __device__ __forceinline__

// ---- problem constants (N=2e6, spatial=[480,360,32], scales=[2,4,1], 8 batches, sorted) ----
constexpr int NPTS       = 2000000;
constexpr int STRIDE_OUT = 18000001;   // per-scale output stride in int32 elements
constexpr int OFF_INV    = 8000000;
constexpr int OFF_COORS  = 10000000;
constexpr int OFF_NUM    = 18000000;

// scale=2: 240x180x16 ; scale=4: 120x90x8 ; scale=1: 480x360x32
constexpr int R2W  = 172800;    // words; per-batch slice 21600 w
constexpr int R4W  = 21600;     // words; per-batch slice 2700 w
constexpr int R1W  = 1382400;   // words; per-(batch,rho/6) slice 28800 w
constexpr int RW0  = 0;
constexpr int RW1  = R2W;
constexpr int RW2  = R2W + R4W;
constexpr int WTOT = R2W + R4W + R1W;       // 1576800
constexpr int J2   = 8;                     // copies/chunks for scale-2/4 hist
constexpr int J1   = 4;                     // copies/chunks for scale-1 hist
constexpr int S1W  = 28800;                 // words per scale-1 hist slice (115.2 KB)
constexpr int S1BITS = S1W * 32;            // 921600 bits per hist slice

// cooperative grid shape: 256 blocks (1/CU, LDS-capped) x 1024 threads
constexpr int NBLK = 256;
constexpr int NTHR = 1024;
constexpr int NT   = NBLK * NTHR;           // 262144 threads
constexpr int CHW  = NTHR * 4;              // 4096 words per scan chunk
constexpr int NCH  = (WTOT + CHW - 1) / CHW;// 385 chunks

// inv-phase virtual-block swizzle (XCD affinity, same as round-1 epilogue)
constexpr int NV   = (NPTS + NTHR - 1) / NTHR;   // 1954 virtual inv blocks
constexpr int NV8  = ((NV + 7) / 8) * 8;         // 1960
constexpr int VQ   = NV8 / 8;                    // 245

// ---- strict (non-contractible) f32 ops: bit-match XLA's mul,mul,add,sqrt ----
DI float fmul_s(float a, float b){ float r; asm("v_mul_f32 %0, %1, %2" : "=v"(r) : "v"(a), "v"(b)); return r; }
DI float fadd_s(float a, float b){ float r; asm("v_add_f32 %0, %1, %2" : "=v"(r) : "v"(a), "v"(b)); return r; }

// ---- merge histogram copies for a 4-word group at word index `base` ----
DI uint4 merged_words(int base, const uint32_t* __restrict__ rep2s,
                      const uint32_t* __restrict__ rep4s,
                      const uint32_t* __restrict__ rep1s) {
  uint4 acc = make_uint4(0, 0, 0, 0);
  if (base < RW1) {
    #pragma unroll
    for (int c = 0; c < J2; ++c) {
      uint4 w = *reinterpret_cast<const uint4*>(rep2s + (size_t)c * R2W + base);
      acc.x |= w.x; acc.y |= w.y; acc.z |= w.z; acc.w |= w.w;
    }
  } else if (base < RW2) {
    int l = base - RW1;
    #pragma unroll
    for (int c = 0; c < J2; ++c) {
      uint4 w = *reinterpret_cast<const uint4*>(rep4s + (size_t)c * R4W + l);
      acc.x |= w.x; acc.y |= w.y; acc.z |= w.z; acc.w |= w.w;
    }
  } else {
    int l = base - RW2;
    #pragma unroll
    for (int c = 0; c < J1; ++c) {
      uint4 w = *reinterpret_cast<const uint4*>(rep1s + (size_t)c * R1W + l);
      acc.x |= w.x; acc.y |= w.y; acc.z |= w.z; acc.w |= w.w;
    }
  }
  return acc;
}

// ---- exact integer key decode (pow2 masks + magic-mul const division) ----
template <int S>
DI int4 decode_key(int key) {   // returns (b, a0, a1, a2)
  constexpr int D0[3] = {240, 120, 480};
  constexpr int D1[3] = {180,  90, 360};
  constexpr int D2[3] = { 16,   8,  32};
  int a2 = key & (D2[S] - 1);
  int r  = key / D2[S];
  int q  = r / D1[S];
  int a1 = r - q * D1[S];
  int b  = q / D0[S];
  int a0 = q - b * D0[S];
  return make_int4(b, a0, a1, a2);
}

template <int S>
DI void coors_word(int wi_local, uint32_t bits, uint32_t rank, int* __restrict__ coors) {
  int keybase = wi_local * 32;
  while (bits) {
    int j = __builtin_ctz(bits);
    bits &= bits - 1;
    int4 d = decode_key<S>(keybase + j);
    *reinterpret_cast<int4*>(coors + (size_t)rank * 4) = make_int4(d.x, d.w, d.z, d.y);  // [b,z,phi,rho]
    ++rank;
  }
}

// ================= fused cooperative kernel: all 6 phases, 1 dispatch =================
__global__ __launch_bounds__(NTHR) void fused(const float4* __restrict__ pts,
                                              const int* __restrict__ batch, int n,
                                              int* __restrict__ keys,
                                              int* __restrict__ bstart,
                                              uint32_t* __restrict__ rep2s,
                                              uint32_t* __restrict__ rep4s,
                                              uint32_t* __restrict__ rep1s,
                                              uint32_t* __restrict__ bits,
                                              uint32_t* __restrict__ chunkSums,
                                              uint2* __restrict__ pairs,
                                              int* __restrict__ out) {
  cg::grid_group grid = cg::this_grid();
  alignas(16) __shared__ uint32_t bmA[S1W];     // 115.2 KB: hist slice / scan scratch
  alignas(16) __shared__ uint32_t bmB[2700];    // 10.8 KB: scale-4 hist slice
  const int t = threadIdx.x;
  const int gtid = (int)blockIdx.x * NTHR + t;

  // ---- P0: per point -> 3 key planes + batch boundary offsets bstart[0..8] ----
  {
    const float PI_F     = 3.14159265358979323846f;
    const float TWO_PI_F = 6.28318530717958647692f;
    constexpr float C0[3] = {239.f, 119.f, 479.f};
    constexpr float C1[3] = {179.f,  89.f, 359.f};
    constexpr float C2[3] = { 15.f,   7.f,  31.f};
    constexpr int   D0[3] = {240, 120, 480};
    constexpr int   D1[3] = {180,  90, 360};
    constexpr int   D2[3] = { 16,   8,  32};
    for (int i = gtid; i < n; i += NT) {
      float4 p = pts[i];
      int bi = batch[i];
      float rho = sqrtf(fadd_s(fmul_s(p.x, p.x), fmul_s(p.y, p.y)));
      float phi = atan2f(p.y, p.x);
      float tr = (fminf(fmaxf(rho, 0.0f), 50.0f) - 0.0f) / 50.0f;
      float tp = (fminf(fmaxf(phi, -PI_F), PI_F) + PI_F) / TWO_PI_F;
      float tz = (fminf(fmaxf(p.z, -4.0f), 2.0f) + 4.0f) / 6.0f;
      #pragma unroll
      for (int s = 0; s < 3; ++s) {
        int a0 = (int)floorf(tr * C0[s]);
        int a1 = (int)floorf(tp * C1[s]);
        int a2 = (int)floorf(tz * C2[s]);
        keys[s * n + i] = ((bi * D0[s] + a0) * D1[s] + a1) * D2[s] + a2;
      }
      if (i == 0) {
        #pragma unroll 1
        for (int k = 0; k <= bi; ++k) bstart[k] = 0;
      }
      int bnext = (i + 1 < n) ? batch[i + 1] : 8;
      #pragma unroll 1
      for (int k = bi + 1; k <= bnext; ++k) bstart[k] = i + 1;
    }
  }
  grid.sync();

  // ---- P1: fused LDS histograms (identical to round-1 hist_all; pb == blockIdx) ----
  {
    int pb = (int)blockIdx.x;
    if (pb < 64) {
      int bv = pb & 7, j = pb >> 3;
      for (int w = t * 4; w < 21600; w += 4096) *reinterpret_cast<uint4*>(bmA + w) = make_uint4(0,0,0,0);
      for (int w = t; w < 2700; w += 1024) bmB[w] = 0;
      __syncthreads();
      int lo = bstart[bv];
      int hi = bstart[bv + 1];
      int sz = hi - lo;
      int s = lo + (int)((long long)sz * j / J2);
      int e = lo + (int)((long long)sz * (j + 1) / J2);
      const int* k0 = keys;
      const int* k1 = keys + n;
      for (int i = s + t; i < e; i += 1024) {
        int ink2 = k0[i] - bv * 691200;   // 240*180*16 bits/batch
        int ink4 = k1[i] - bv * 86400;    // 120*90*8 bits/batch
        atomicOr(&bmA[ink2 >> 5], 1u << (ink2 & 31));
        atomicOr(&bmB[ink4 >> 5], 1u << (ink4 & 31));
      }
      __syncthreads();
      uint32_t* d2 = rep2s + (size_t)j * R2W + bv * 21600;
      uint32_t* d4 = rep4s + (size_t)j * R4W + bv * 2700;
      for (int w = t * 4; w < 21600; w += 4096) *reinterpret_cast<uint4*>(d2 + w) = *reinterpret_cast<uint4*>(bmA + w);
      for (int w = t * 4; w < 2700; w += 4096) *reinterpret_cast<uint4*>(d4 + w) = *reinterpret_cast<uint4*>(bmB + w);
    } else {
      int bv = pb & 7;                    // XCD == batch
      int id = (pb - 64) >> 3;            // [0, 24): (j, r) slot on this XCD
      int j = id / 6, r = id - j * 6;
      int slice = bv * 6 + r;
      for (int w = t * 4; w < S1W; w += 4096) *reinterpret_cast<uint4*>(bmA + w) = make_uint4(0,0,0,0);
      __syncthreads();
      int lo = bstart[bv];
      int hi = bstart[bv + 1];
      int sz = hi - lo;
      int s = lo + (int)((long long)sz * j / J1);
      int e = lo + (int)((long long)sz * (j + 1) / J1);
      const int* k2 = keys + 2 * n;
      int base = bv * 5529600 + r * S1BITS;
      for (int i = s + t; i < e; i += 1024) {
        int rel = k2[i] - base;           // in [0, S1BITS) iff in our rho range
        if ((unsigned)rel < (unsigned)S1BITS) atomicOr(&bmA[rel >> 5], 1u << (rel & 31));
      }
      __syncthreads();
      uint32_t* d = rep1s + (size_t)j * R1W + (size_t)slice * S1W;
      for (int w = t * 4; w < S1W; w += 4096) *reinterpret_cast<uint4*>(d + w) = *reinterpret_cast<uint4*>(bmA + w);
    }
  }
  grid.sync();

  // ---- P2: merge copies -> bits[], per-chunk popcount sums (4096-word chunks) ----
  for (int v = (int)blockIdx.x; v < NCH; v += NBLK) {
    int base = v * CHW + t * 4;
    uint32_t s = 0;
    if (base < WTOT) {       // WTOT%4==0; regions 4-aligned
      uint4 m = merged_words(base, rep2s, rep4s, rep1s);
      *reinterpret_cast<uint4*>(bits + base) = m;
      s = __popc(m.x) + __popc(m.y) + __popc(m.z) + __popc(m.w);
    }
    __syncthreads();
    bmA[t] = s;
    __syncthreads();
    for (int off = 512; off > 0; off >>= 1) { if (t < off) bmA[t] += bmA[t + off]; __syncthreads(); }
    if (t == 0) chunkSums[v] = bmA[0];
  }
  grid.sync();

  // ---- P3: per-word (bits, excl-prefix) pairs; chunk base summed in-block ----
  for (int v = (int)blockIdx.x; v < NCH; v += NBLK) {
    uint32_t bs = (t < v) ? chunkSums[t] : 0u;   // NCH=385 < 1024
    __syncthreads();
    bmA[t] = bs;
    __syncthreads();
    for (int off = 512; off > 0; off >>= 1) { if (t < off) bmA[t] += bmA[t + off]; __syncthreads(); }
    uint32_t chunkBase = bmA[0];
    __syncthreads();
    int base = v * CHW + t * 4;
    uint32_t b4[4] = {0,0,0,0}; uint32_t c4[4]; uint32_t sum = 0;
    if (base < WTOT) {
      uint4 w = *reinterpret_cast<const uint4*>(bits + base);
      b4[0] = w.x; b4[1] = w.y; b4[2] = w.z; b4[3] = w.w;
    }
    #pragma unroll
    for (int k = 0; k < 4; ++k) { c4[k] = __popc(b4[k]); sum += c4[k]; }
    bmA[t] = sum;
    __syncthreads();
    for (int off = 1; off < 1024; off <<= 1) {
      uint32_t x = (t >= off) ? bmA[t - off] : 0u;
      __syncthreads();
      bmA[t] += x;
      __syncthreads();
    }
    uint32_t excl = bmA[t] - sum + chunkBase;
    if (base < WTOT) {
      #pragma unroll
      for (int k = 0; k < 4; ++k) { pairs[base + k] = make_uint2(b4[k], excl); excl += c4[k]; }
    }
    __syncthreads();
  }
  grid.sync();

  // ---- P4: epilogue — inv (XCD-swizzled, gather-based) | coors | tail ----
  {
    uint32_t subs1 = pairs[RW1].y;
    uint32_t subs2 = pairs[RW2].y;

    // inv + bxyz: virtual block swizzle keeps per-batch pairs gathers XCD-affine
    for (int vb = (int)blockIdx.x; vb < NV8; vb += NBLK) {
      int lv = (vb & 7) * VQ + (vb >> 3);
      if (lv >= NV) continue;
      int i = lv * NTHR + t;
      if (i >= n) continue;
      int k0v = keys[i], k1v = keys[n + i], k2v = keys[2 * n + i];
      *reinterpret_cast<int4*>(out + 0 * STRIDE_OUT + (size_t)i * 4) = decode_key<0>(k0v);
      *reinterpret_cast<int4*>(out + 1 * STRIDE_OUT + (size_t)i * 4) = decode_key<1>(k1v);
      *reinterpret_cast<int4*>(out + 2 * STRIDE_OUT + (size_t)i * 4) = decode_key<2>(k2v);
      {
        uint2 pr = pairs[RW0 + (k0v >> 5)];
        out[0 * STRIDE_OUT + OFF_INV + i] = (int)(pr.y + __popc(pr.x & ((1u << (k0v & 31)) - 1u)));
      }
      {
        uint2 pr = pairs[RW1 + (k1v >> 5)];
        out[1 * STRIDE_OUT + OFF_INV + i] = (int)(pr.y - subs1 + __popc(pr.x & ((1u << (k1v & 31)) - 1u)));
      }
      {
        uint2 pr = pairs[RW2 + (k2v >> 5)];
        out[2 * STRIDE_OUT + OFF_INV + i] = (int)(pr.y - subs2 + __popc(pr.x & ((1u << (k2v & 31)) - 1u)));
      }
    }

    // coors: one bitmap word per thread, rows in rank order
    for (int wi = gtid; wi < WTOT; wi += NT) {
      uint2 pr = pairs[wi];
      if (!pr.x) continue;
      if (wi < RW1)      coors_word<0>(wi,       pr.x, pr.y,         out + 0 * STRIDE_OUT + OFF_COORS);
      else if (wi < RW2) coors_word<1>(wi - RW1, pr.x, pr.y - subs1, out + 1 * STRIDE_OUT + OFF_COORS);
      else               coors_word<2>(wi - RW2, pr.x, pr.y - subs2, out + 2 * STRIDE_OUT + OFF_COORS);
    }

    // tail: zero rows [num, n) per scale; write num
    uint2 last = pairs[WTOT - 1];
    uint32_t total = last.y + (uint32_t)__popc(last.x);
    uint32_t num0 = subs1;
    uint32_t num1 = subs2 - subs1;
    uint32_t num2 = total - subs2;
    if (gtid == 0) {
      out[0 * STRIDE_OUT + OFF_NUM] = (int)num0;
      out[1 * STRIDE_OUT + OFF_NUM] = (int)num1;
      out[2 * STRIDE_OUT + OFF_NUM] = (int)num2;
    }
    for (int idx = gtid; idx < 3 * n; idx += NT) {
      int s = 0, i = idx;
      if (i >= 2 * n)  { s = 2; i -= 2 * n; }
      else if (i >= n) { s = 1; i -= n; }
      uint32_t num = (s == 0) ? num0 : (s == 1) ? num1 : num2;
      if ((uint32_t)i >= num)
        *reinterpret_cast<int4*>(out + s * STRIDE_OUT + OFF_COORS + (size_t)i * 4) = make_int4(0, 0, 0, 0);
    }
  }
}

extern "C" void kernel_launch(void* const* d_in, const int* in_sizes, int n_in,
                              void* d_out, int out_size, void* d_ws, size_t ws_size,
                              hipStream_t stream) {
  const float4* pts   = (const float4*)d_in[0];
  const int*    batch = (const int*)d_in[1];
  int n = in_sizes[1];  // 2,000,000
  int* out = (int*)d_out;

  // ws: rep2s | rep4s | rep1s | bits | pairs | chunkSums | bstart | keys  (~72 MB, no memsets)
  uint32_t* rep2s     = (uint32_t*)d_ws;
  uint32_t* rep4s     = rep2s + (size_t)J2 * R2W;
  uint32_t* rep1s     = rep4s + (size_t)J2 * R4W;
  uint32_t* bits      = rep1s + (size_t)J1 * R1W;
  uint2*    pairs     = (uint2*)(bits + WTOT);
  uint32_t* chunkSums = (uint32_t*)(pairs + WTOT);
  int*      bstart    = (int*)(chunkSums + NCH + 15);
  int*      keys      = (int*)(bstart + 16);

  void* args[12] = { (void*)&pts, (void*)&batch, (void*)&n, (void*)&keys, (void*)&bstart,
                     (void*)&rep2s, (void*)&rep4s, (void*)&rep1s, (void*)&bits,
                     (void*)&chunkSums, (void*)&pairs, (void*)&out };
  hipLaunchCooperativeKernel(reinterpret_cast<void*>(fused), dim3(NBLK), dim3(NTHR),
                             args, 0, stream);
}

// Round 6
// 333.789 us; speedup vs baseline: 1.4960x; 1.4960x over previous
//
#include <hip/hip_runtime.h>
#include <cstdint>

#define DI __device__ __forceinline__

// ---- problem constants (N=2e6, spatial=[480,360,32], scales=[2,4,1], 8 batches, sorted) ----
constexpr int NPTS       = 2000000;
constexpr int STRIDE_OUT = 18000001;   // per-scale output stride in int32 elements
constexpr int OFF_INV    = 8000000;
constexpr int OFF_COORS  = 10000000;
constexpr int OFF_NUM    = 18000000;

// scale=2: 240x180x16 ; scale=4: 120x90x8 ; scale=1: 480x360x32
constexpr int R2W  = 172800;    // words; per-batch slice 21600 w
constexpr int R4W  = 21600;     // words; per-batch slice 2700 w
constexpr int R1W  = 1382400;   // words; per-(batch,rho/6) slice 28800 w
constexpr int RW0  = 0;
constexpr int RW1  = R2W;
constexpr int RW2  = R2W + R4W;
constexpr int WTOT = R2W + R4W + R1W;       // 1576800
constexpr int NB1  = (WTOT + 1023) / 1024;  // scan blocks (1540)
constexpr int J2   = 8;                     // copies/chunks for scale-2/4 hist
constexpr int J1   = 4;                     // copies/chunks for scale-1 hist
constexpr int S1W  = 28800;                 // words per scale-1 hist slice
constexpr int S1BITS = S1W * 32;            // 921600 bits per hist slice

// epilogue block partition: inv blocks are 256 thr x 4 points (MLP), XCD-swizzled
constexpr int NBLK_INVU  = (NPTS + 1023) / 1024;       // 1954
constexpr int NBLK_INVUP = ((NBLK_INVU + 7) / 8) * 8;  // 1960
constexpr int IVQ        = NBLK_INVUP / 8;             // 245
constexpr int NBLK_COORS = (WTOT + 255) / 256;         // 6160
constexpr int NBLK_TAIL  = (3 * NPTS + 255) / 256;     // 23438

// ---- strict (non-contractible) f32 ops: bit-match XLA's mul,mul,add,sqrt ----
DI float fmul_s(float a, float b){ float r; asm("v_mul_f32 %0, %1, %2" : "=v"(r) : "v"(a), "v"(b)); return r; }
DI float fadd_s(float a, float b){ float r; asm("v_add_f32 %0, %1, %2" : "=v"(r) : "v"(a), "v"(b)); return r; }

// ---- pass 1: per point -> 3 key planes + bxyz rows (exact pre-encode ints) + bstart ----
__global__ __launch_bounds__(256) void pass_keys(const float4* __restrict__ pts,
                                                 const int* __restrict__ batch, int n,
                                                 int* __restrict__ keys,
                                                 int* __restrict__ bstart,
                                                 int* __restrict__ out) {
  int i = blockIdx.x * 256 + threadIdx.x;
  if (i >= n) return;
  float4 p = pts[i];
  int bi = batch[i];
  const float PI_F     = 3.14159265358979323846f;
  const float TWO_PI_F = 6.28318530717958647692f;
  float rho = sqrtf(fadd_s(fmul_s(p.x, p.x), fmul_s(p.y, p.y)));
  float phi = atan2f(p.y, p.x);
  float tr = (fminf(fmaxf(rho, 0.0f), 50.0f) - 0.0f) / 50.0f;
  float tp = (fminf(fmaxf(phi, -PI_F), PI_F) + PI_F) / TWO_PI_F;
  float tz = (fminf(fmaxf(p.z, -4.0f), 2.0f) + 4.0f) / 6.0f;
  constexpr float C0[3] = {239.f, 119.f, 479.f};
  constexpr float C1[3] = {179.f,  89.f, 359.f};
  constexpr float C2[3] = { 15.f,   7.f,  31.f};
  constexpr int   D0[3] = {240, 120, 480};
  constexpr int   D1[3] = {180,  90, 360};
  constexpr int   D2[3] = { 16,   8,  32};
  #pragma unroll
  for (int s = 0; s < 3; ++s) {
    int a0 = (int)floorf(tr * C0[s]);
    int a1 = (int)floorf(tp * C1[s]);
    int a2 = (int)floorf(tz * C2[s]);
    keys[s * n + i] = ((bi * D0[s] + a0) * D1[s] + a1) * D2[s] + a2;
    *reinterpret_cast<int4*>(out + s * STRIDE_OUT + (size_t)i * 4) = make_int4(bi, a0, a1, a2);
  }
  // batch is sorted: record boundaries (few threads write; loads are L1/L2-hot)
  if (i == 0) {
    #pragma unroll 1
    for (int k = 0; k <= bi; ++k) bstart[k] = 0;
  }
  int bnext = (i + 1 < n) ? batch[i + 1] : 8;
  #pragma unroll 1
  for (int k = bi + 1; k <= bnext; ++k) bstart[k] = i + 1;
}

// ---- pass 2: fused LDS histograms, 256 blocks (one occupancy wave), x4-unrolled loads
// for memory-level parallelism (latency-bound fix from round-5 counters). ----
__global__ __launch_bounds__(1024) void hist_all(const int* __restrict__ bstart,
                                                 const int* __restrict__ keys, int n,
                                                 uint32_t* __restrict__ rep2s,
                                                 uint32_t* __restrict__ rep4s,
                                                 uint32_t* __restrict__ rep1s) {
  alignas(16) __shared__ uint32_t bmA[S1W];     // scale-1 slice / scale-2 slice (first 21600)
  alignas(16) __shared__ uint32_t bmB[2700];    // scale-4 slice (2/4 role only)
  int t = threadIdx.x;
  int pb = blockIdx.x;
  if (pb < 64) {
    int bv = pb & 7, j = pb >> 3;               // XCD (pb&7) handles batch bv
    for (int w = t * 4; w < 21600; w += 4096) *reinterpret_cast<uint4*>(bmA + w) = make_uint4(0,0,0,0);
    for (int w = t; w < 2700; w += 1024) bmB[w] = 0;
    __syncthreads();
    int lo = bstart[bv];
    int hi = bstart[bv + 1];
    int sz = hi - lo;
    int s = lo + (int)((long long)sz * j / J2);
    int e = lo + (int)((long long)sz * (j + 1) / J2);
    const int* k0 = keys;
    const int* k1 = keys + n;
    int b2 = bv * 691200;   // 240*180*16 bits/batch
    int b4 = bv * 86400;    // 120*90*8 bits/batch
    int i = s + t;
    for (; i < e - 3072; i += 4096) {   // 8 independent loads in flight per iter
      int a0 = k0[i], a1 = k0[i + 1024], a2 = k0[i + 2048], a3 = k0[i + 3072];
      int c0 = k1[i], c1 = k1[i + 1024], c2 = k1[i + 2048], c3 = k1[i + 3072];
      int x0 = a0 - b2, x1 = a1 - b2, x2 = a2 - b2, x3 = a3 - b2;
      int y0 = c0 - b4, y1 = c1 - b4, y2 = c2 - b4, y3 = c3 - b4;
      atomicOr(&bmA[x0 >> 5], 1u << (x0 & 31));
      atomicOr(&bmA[x1 >> 5], 1u << (x1 & 31));
      atomicOr(&bmA[x2 >> 5], 1u << (x2 & 31));
      atomicOr(&bmA[x3 >> 5], 1u << (x3 & 31));
      atomicOr(&bmB[y0 >> 5], 1u << (y0 & 31));
      atomicOr(&bmB[y1 >> 5], 1u << (y1 & 31));
      atomicOr(&bmB[y2 >> 5], 1u << (y2 & 31));
      atomicOr(&bmB[y3 >> 5], 1u << (y3 & 31));
    }
    for (; i < e; i += 1024) {
      int ink2 = k0[i] - b2;
      int ink4 = k1[i] - b4;
      atomicOr(&bmA[ink2 >> 5], 1u << (ink2 & 31));
      atomicOr(&bmB[ink4 >> 5], 1u << (ink4 & 31));
    }
    __syncthreads();
    uint32_t* d2 = rep2s + (size_t)j * R2W + bv * 21600;
    uint32_t* d4 = rep4s + (size_t)j * R4W + bv * 2700;
    for (int w = t * 4; w < 21600; w += 4096) *reinterpret_cast<uint4*>(d2 + w) = *reinterpret_cast<uint4*>(bmA + w);
    for (int w = t * 4; w < 2700; w += 4096) *reinterpret_cast<uint4*>(d4 + w) = *reinterpret_cast<uint4*>(bmB + w);
  } else {
    int bv = pb & 7;                    // XCD == batch
    int id = (pb - 64) >> 3;            // [0, 24): (j, r) slot on this XCD
    int j = id / 6, r = id - j * 6;
    int slice = bv * 6 + r;
    for (int w = t * 4; w < S1W; w += 4096) *reinterpret_cast<uint4*>(bmA + w) = make_uint4(0,0,0,0);
    __syncthreads();
    int lo = bstart[bv];
    int hi = bstart[bv + 1];
    int sz = hi - lo;
    int s = lo + (int)((long long)sz * j / J1);
    int e = lo + (int)((long long)sz * (j + 1) / J1);
    const int* k2 = keys + 2 * n;
    int base = bv * 5529600 + r * S1BITS;
    int i = s + t;
    for (; i < e - 3072; i += 4096) {   // 4 independent loads in flight per iter
      int r0 = k2[i] - base, r1 = k2[i + 1024] - base;
      int r2 = k2[i + 2048] - base, r3 = k2[i + 3072] - base;
      if ((unsigned)r0 < (unsigned)S1BITS) atomicOr(&bmA[r0 >> 5], 1u << (r0 & 31));
      if ((unsigned)r1 < (unsigned)S1BITS) atomicOr(&bmA[r1 >> 5], 1u << (r1 & 31));
      if ((unsigned)r2 < (unsigned)S1BITS) atomicOr(&bmA[r2 >> 5], 1u << (r2 & 31));
      if ((unsigned)r3 < (unsigned)S1BITS) atomicOr(&bmA[r3 >> 5], 1u << (r3 & 31));
    }
    for (; i < e; i += 1024) {
      int rel = k2[i] - base;
      if ((unsigned)rel < (unsigned)S1BITS) atomicOr(&bmA[rel >> 5], 1u << (rel & 31));
    }
    __syncthreads();
    uint32_t* d = rep1s + (size_t)j * R1W + (size_t)slice * S1W;
    for (int w = t * 4; w < S1W; w += 4096) *reinterpret_cast<uint4*>(d + w) = *reinterpret_cast<uint4*>(bmA + w);
  }
}

// ---- merge copies for a 4-word group at word index `base` ----
DI uint4 merged_words(int base, const uint32_t* __restrict__ rep2s,
                      const uint32_t* __restrict__ rep4s,
                      const uint32_t* __restrict__ rep1s) {
  uint4 acc = make_uint4(0, 0, 0, 0);
  if (base < RW1) {
    #pragma unroll
    for (int c = 0; c < J2; ++c) {
      uint4 w = *reinterpret_cast<const uint4*>(rep2s + (size_t)c * R2W + base);
      acc.x |= w.x; acc.y |= w.y; acc.z |= w.z; acc.w |= w.w;
    }
  } else if (base < RW2) {
    int l = base - RW1;
    #pragma unroll
    for (int c = 0; c < J2; ++c) {
      uint4 w = *reinterpret_cast<const uint4*>(rep4s + (size_t)c * R4W + l);
      acc.x |= w.x; acc.y |= w.y; acc.z |= w.z; acc.w |= w.w;
    }
  } else {
    int l = base - RW2;
    #pragma unroll
    for (int c = 0; c < J1; ++c) {
      uint4 w = *reinterpret_cast<const uint4*>(rep1s + (size_t)c * R1W + l);
      acc.x |= w.x; acc.y |= w.y; acc.z |= w.z; acc.w |= w.w;
    }
  }
  return acc;
}

// ---- pass 3: scanA — merge on the fly, write bits[] + per-block popcount sums ----
__global__ __launch_bounds__(256) void scanA(const uint32_t* __restrict__ rep2s,
                                             const uint32_t* __restrict__ rep4s,
                                             const uint32_t* __restrict__ rep1s,
                                             uint32_t* __restrict__ bits,
                                             uint32_t* __restrict__ blockSums) {
  __shared__ uint32_t lds[256];
  int t = threadIdx.x;
  int base = blockIdx.x * 1024 + t * 4;
  uint32_t s = 0;
  if (base < WTOT) {       // WTOT%4==0; regions 4-aligned
    uint4 m = merged_words(base, rep2s, rep4s, rep1s);
    *reinterpret_cast<uint4*>(bits + base) = m;
    s = __popc(m.x) + __popc(m.y) + __popc(m.z) + __popc(m.w);
  }
  lds[t] = s; __syncthreads();
  for (int off = 128; off > 0; off >>= 1) { if (t < off) lds[t] += lds[t + off]; __syncthreads(); }
  if (t == 0) blockSums[blockIdx.x] = lds[0];
}

// ---- pass 4: scanC — per-word (bits, excl-prefix) pairs ----
__global__ __launch_bounds__(256) void scanC(const uint32_t* __restrict__ bits,
                                             const uint32_t* __restrict__ blockSums,
                                             uint2* __restrict__ pairs) {
  __shared__ uint32_t lds[256];
  int t = threadIdx.x;
  uint32_t bs = 0;
  for (int k = t; k < (int)blockIdx.x; k += 256) bs += blockSums[k];
  lds[t] = bs; __syncthreads();
  for (int off = 128; off > 0; off >>= 1) { if (t < off) lds[t] += lds[t + off]; __syncthreads(); }
  uint32_t blockBase = lds[0];
  __syncthreads();
  int base = blockIdx.x * 1024 + t * 4;
  uint32_t b[4] = {0,0,0,0}; uint32_t c[4]; uint32_t sum = 0;
  if (base < WTOT) {
    uint4 w = *reinterpret_cast<const uint4*>(bits + base);
    b[0] = w.x; b[1] = w.y; b[2] = w.z; b[3] = w.w;
  }
  #pragma unroll
  for (int k = 0; k < 4; ++k) { c[k] = __popc(b[k]); sum += c[k]; }
  lds[t] = sum; __syncthreads();
  for (int off = 1; off < 256; off <<= 1) {
    uint32_t x = (t >= off) ? lds[t - off] : 0u; __syncthreads();
    lds[t] += x; __syncthreads();
  }
  uint32_t excl = lds[t] - sum + blockBase;
  if (base < WTOT) {
    #pragma unroll
    for (int k = 0; k < 4; ++k) { pairs[base + k] = make_uint2(b[k], excl); excl += c[k]; }
  }
}

// ---- exact integer key decode (pow2 masks + magic-mul const division) ----
template <int S>
DI int4 decode_key(int key) {   // returns (b, a0, a1, a2)
  constexpr int D0[3] = {240, 120, 480};
  constexpr int D1[3] = {180,  90, 360};
  constexpr int D2[3] = { 16,   8,  32};
  int a2 = key & (D2[S] - 1);
  int r  = key / D2[S];
  int q  = r / D1[S];
  int a1 = r - q * D1[S];
  int b  = q / D0[S];
  int a0 = q - b * D0[S];
  return make_int4(b, a0, a1, a2);
}

template <int S>
DI void coors_word(int wi_local, uint32_t bits, uint32_t rank, int* __restrict__ coors) {
  int keybase = wi_local * 32;
  while (bits) {
    int j = __builtin_ctz(bits);
    bits &= bits - 1;
    int4 d = decode_key<S>(keybase + j);
    *reinterpret_cast<int4*>(coors + (size_t)rank * 4) = make_int4(d.x, d.w, d.z, d.y);  // [b,z,phi,rho]
    ++rank;
  }
}

// ---- pass 5: fused epilogue — inv (4 pts/thread, batched loads->gathers) | coors | tail.
// inv virtual blocks XCD-swizzled ((b&7)*IVQ + b>>3) for per-batch pairs L2 affinity. ----
__global__ __launch_bounds__(256) void epilogue(int n, const uint2* __restrict__ pairs,
                                                const int* __restrict__ keys,
                                                int* __restrict__ out) {
  int b = blockIdx.x;
  int t = threadIdx.x;
  if (b < NBLK_INVUP) {
    int lv = (b & 7) * IVQ + (b >> 3);
    if (lv >= NBLK_INVU) return;
    int i0 = lv * 1024 + t;
    uint32_t subs1 = pairs[RW1].y;
    uint32_t subs2 = pairs[RW2].y;
    int kv[3][4];
    bool ok[4];
    #pragma unroll
    for (int u = 0; u < 4; ++u) {           // 12 coalesced key loads, all in flight
      int i = i0 + u * 256;
      ok[u] = (i < n);
      int ii = ok[u] ? i : 0;
      kv[0][u] = keys[ii];
      kv[1][u] = keys[n + ii];
      kv[2][u] = keys[2 * n + ii];
    }
    uint2 pr[3][4];
    #pragma unroll
    for (int u = 0; u < 4; ++u) {           // 12 independent random gathers in flight
      pr[0][u] = pairs[RW0 + (kv[0][u] >> 5)];
      pr[1][u] = pairs[RW1 + (kv[1][u] >> 5)];
      pr[2][u] = pairs[RW2 + (kv[2][u] >> 5)];
    }
    #pragma unroll
    for (int u = 0; u < 4; ++u) {
      if (!ok[u]) continue;
      int i = i0 + u * 256;
      out[0 * STRIDE_OUT + OFF_INV + i] =
          (int)(pr[0][u].y + __popc(pr[0][u].x & ((1u << (kv[0][u] & 31)) - 1u)));
      out[1 * STRIDE_OUT + OFF_INV + i] =
          (int)(pr[1][u].y - subs1 + __popc(pr[1][u].x & ((1u << (kv[1][u] & 31)) - 1u)));
      out[2 * STRIDE_OUT + OFF_INV + i] =
          (int)(pr[2][u].y - subs2 + __popc(pr[2][u].x & ((1u << (kv[2][u] & 31)) - 1u)));
    }
  } else if (b < NBLK_INVUP + NBLK_COORS) {
    // ---- coors: one bitmap word per thread, rows in rank order ----
    int wi = (b - NBLK_INVUP) * 256 + t;
    if (wi >= WTOT) return;
    uint2 pr = pairs[wi];
    if (!pr.x) return;
    if (wi < RW1)      coors_word<0>(wi,       pr.x, pr.y,                 out + 0 * STRIDE_OUT + OFF_COORS);
    else if (wi < RW2) coors_word<1>(wi - RW1, pr.x, pr.y - pairs[RW1].y,  out + 1 * STRIDE_OUT + OFF_COORS);
    else               coors_word<2>(wi - RW2, pr.x, pr.y - pairs[RW2].y,  out + 2 * STRIDE_OUT + OFF_COORS);
  } else {
    // ---- tail: one int4 row per thread; zero rows [num, n); write num ----
    int idx = (b - NBLK_INVUP - NBLK_COORS) * 256 + t;   // row in [0, 3n)
    if (idx >= 3 * n) return;
    int s = 0, i = idx;
    if (i >= 2 * n)  { s = 2; i -= 2 * n; }
    else if (i >= n) { s = 1; i -= n; }
    uint2 last = pairs[WTOT - 1];
    uint32_t total = last.y + (uint32_t)__popc(last.x);
    uint32_t lo = (s == 0) ? 0u : pairs[(s == 1) ? RW1 : RW2].y;
    uint32_t hi = (s == 0) ? pairs[RW1].y : (s == 1) ? pairs[RW2].y : total;
    uint32_t num = hi - lo;
    if (i == 0) out[s * STRIDE_OUT + OFF_NUM] = (int)num;
    if ((uint32_t)i >= num)
      *reinterpret_cast<int4*>(out + s * STRIDE_OUT + OFF_COORS + (size_t)i * 4) = make_int4(0, 0, 0, 0);
  }
}

extern "C" void kernel_launch(void* const* d_in, const int* in_sizes, int n_in,
                              void* d_out, int out_size, void* d_ws, size_t ws_size,
                              hipStream_t stream) {
  const float4* pts   = (const float4*)d_in[0];
  const int*    batch = (const int*)d_in[1];
  int n = in_sizes[1];  // 2,000,000
  int* out = (int*)d_out;

  // ws: rep2s | rep4s | rep1s | bits | pairs | blockSums | bstart | keys  (~72 MB, no memsets)
  uint32_t* rep2s     = (uint32_t*)d_ws;
  uint32_t* rep4s     = rep2s + (size_t)J2 * R2W;
  uint32_t* rep1s     = rep4s + (size_t)J2 * R4W;
  uint32_t* bits      = rep1s + (size_t)J1 * R1W;
  uint2*    pairs     = (uint2*)(bits + WTOT);
  uint32_t* blockSums = (uint32_t*)(pairs + WTOT);
  int*      bstart    = (int*)(blockSums + NB1);
  int*      keys      = (int*)(bstart + 16);

  int nblk = (n + 255) / 256;
  pass_keys<<<nblk, 256, 0, stream>>>(pts, batch, n, keys, bstart, out);
  hist_all<<<256, 1024, 0, stream>>>(bstart, keys, n, rep2s, rep4s, rep1s);
  scanA<<<NB1, 256, 0, stream>>>(rep2s, rep4s, rep1s, bits, blockSums);
  scanC<<<NB1, 256, 0, stream>>>(bits, blockSums, pairs);
  epilogue<<<NBLK_INVUP + NBLK_COORS + NBLK_TAIL, 256, 0, stream>>>(n, pairs, keys, out);
}